// Round 7
// baseline (479.546 us; speedup 1.0000x reference)
//
#include <hip/hip_runtime.h>

typedef _Float16 half8 __attribute__((ext_vector_type(8)));
typedef float    f32x4 __attribute__((ext_vector_type(4)));

#define LDS_BYTES (131072 + 512)   // S_gates 64K | S_cx 64K | t double-buffer

__device__ __forceinline__ float rcpf(float x) { return __builtin_amdgcn_rcpf(x); }
__device__ __forceinline__ float sigf(float x)  { return rcpf(1.0f + __expf(-x)); }
__device__ __forceinline__ float tanhf_(float x){ return 1.0f - 2.0f * rcpf(1.0f + __expf(2.0f * x)); }

// ---------------- prepack: fp32 weights -> f16 MFMA-fragment granules in ws ----------------
// Gate granules (1 MiB @ wp+0): id = ((hb*16 + s)*4 + g), 1 KiB each  [hb-major: one wave's
//   K-stream = contiguous 64 KiB; the 4 gates of a k-slice are imm offsets 0..3072].
//   Lane l byte l*16, elem e = W[g*256 + hb*16 + (l&15)][s*32 + (l>>4)*8 + e]; K=512=[Wih|Whh].
// Decomp granules (128 KiB @ wp+1MiB): id = (hb*8 + s), value = Wd[k][h] (f16 hi; lo
//   correction comes from splitting cx, reusing the SAME B fragment for both passes).
__global__ __launch_bounds__(512) void prepack_kernel(
    const float* __restrict__ wih, const float* __restrict__ whh,
    const float* __restrict__ wd, char* __restrict__ wp)
{
  int idx = blockIdx.x * 512 + threadIdx.x;
  if (idx < 65536) {                       // gates: 8 consecutive k per thread
    int n  = idx >> 6;                     // 0..1023 = g*256 + h
    int k8 = (idx & 63) << 3;              // 0..504
    const float* src = (k8 < 256) ? (wih + n * 256 + k8) : (whh + n * 256 + (k8 - 256));
    f32x4 v0 = *(const f32x4*)src;
    f32x4 v1 = *(const f32x4*)(src + 4);
    half8 hv;
#pragma unroll
    for (int e = 0; e < 4; ++e) { hv[e] = (_Float16)v0[e]; hv[e + 4] = (_Float16)v1[e]; }
    int g = n >> 8, h = n & 255;
    int gran = (((h >> 4) << 4) + (k8 >> 5)) * 4 + g;
    int lane = (h & 15) + (((k8 >> 3) & 3) << 4);
    *(half8*)(wp + (gran << 10) + (lane << 4)) = hv;
  } else {                                 // decomp: scalar (coalesced reads over h)
    int i2 = idx - 65536;
    int h = i2 & 255, k = i2 >> 8;
    float v = wd[k * 256 + h];
    int gran = ((h >> 4) << 3) + (k >> 5);
    int lane = (h & 15) + (((k >> 3) & 3) << 4);
    *(_Float16*)(wp + (1 << 20) + (gran << 10) + (lane << 4) + ((k & 7) << 1)) = (_Float16)v;
  }
}

// ---------------- fused TA-LSTM cell: persistent 2-phase pipeline, reg-peak < 128 ----------------
// 256 blocks (1/CU) x 1024 thr (16 waves); block owns 4 tiles of 64 rows x 256 h.
// Budget: 128 unified VGPR+AGPR per wave (16 waves/CU).  Explicit liveness plan:
//   A s-loop:  acc 64 + nb 32 + (cv 16 only s=10..end) + misc        ~= 120 peak
//   A cv-flush: acc 64 + cv 16 (dies) + misc                          ~= 95
//   A finish (per-m interleaved): acc<=64 (quarter dies per m) + packed 12 + tmp 12 ~= 95
//   B: packed 12 + accd 16 + nbd 8 + sva/svb 16 window + misc         ~= 80
// Gate results packed f16 (i*g, f, o in (-1,1); 5e-4 rel err -> cy err ~0.1 << 4198 thr).
__global__ __launch_bounds__(1024, 4) void talstm_kernel(
    const float* __restrict__ inp, const float* __restrict__ tt,
    const float* __restrict__ hx,  const float* __restrict__ cx,
    const float* __restrict__ bih, const float* __restrict__ bhh,
    const float* __restrict__ bd,  const char* __restrict__ wp,
    float* __restrict__ out)
{
  extern __shared__ __align__(16) char smem[];
  float* tsh = (float*)(smem + 131072);    // 2 x 64 floats
  const int tid  = threadIdx.x;
  const int lane = tid & 63;
  const int w    = __builtin_amdgcn_readfirstlane(tid >> 6);   // wave id = h-block (0..15)
  const int l15  = lane & 15;
  const int kq8  = (lane >> 4) << 3;
  const int laneB = lane << 4;
  const int tile0 = blockIdx.x << 2;

  // per-thread epilogue constants
  const int h  = (w << 4) + l15;
  const float bi  = bih[h]       + bhh[h];
  const float bfg = bih[256 + h] + bhh[256 + h];
  const float bg  = bih[512 + h] + bhh[512 + h];
  const float bo  = bih[768 + h] + bhh[768 + h];
  const float bdv = bd[h];
  const int er   = (lane >> 4) << 2;
  const int hoff = ((w >> 1) << 10) + ((((w & 1) << 1) + (l15 >> 3)) << 8) + ((l15 & 7) << 1);

  const char* a0 = smem + laneB;           // S_gates
  const char* a1 = smem + 65536 + laneB;   // S_cx hi (lo at +32768)
  const char* wgp = wp + (w << 16) + laneB;              // gates: s at +s*4096, g at +g*1024
  const char* wdp = wp + (1 << 20) + (w << 13) + laneB;  // decomp: s at +s*1024

  // ---- prologue: stage in+hx(tile0) + t(tile0) ----
  {
    const int rb0 = tile0 << 6;
#pragma unroll
    for (int gi = 0; gi < 4; ++gi) {
      int gid = (w << 2) + gi;             // sec(1)|m(2)|s(3)
      int sec = gid >> 5, m = (gid >> 3) & 3, ss = gid & 7;
      const float* p = (sec ? hx : inp) + (size_t)(rb0 + (m << 4) + l15) * 256 + (ss << 5) + kq8;
      f32x4 v0 = *(const f32x4*)p, v1 = *(const f32x4*)(p + 4);
      half8 hv;
#pragma unroll
      for (int e = 0; e < 4; ++e) { hv[e] = (_Float16)v0[e]; hv[e + 4] = (_Float16)v1[e]; }
      *(half8*)(smem + (gid << 10) + laneB) = hv;
    }
    if (tid < 64) tsh[tid] = tt[rb0 + tid];
  }
  __syncthreads();

#pragma unroll 1
  for (int it = 0; it < 4; ++it) {
    const int rbase = (tile0 + it) << 6;
    const bool more = (it < 3);
    const f32x4 fz = {0.f, 0.f, 0.f, 0.f};

    // packed gate results (live into phase B): slot = m*4+e -> vec m>>1, elem (m&1)*4+e
    half8 pk_i[2], pk_f[2], pk_o[2];       // 12 VGPRs total

    // ================= PHASE A: gates MFMA + cx stage =================
    {
      f32x4 acc[4][4];
#pragma unroll
      for (int g = 0; g < 4; ++g)
#pragma unroll
        for (int m = 0; m < 4; ++m) acc[g][m] = fz;

      half8 nb0 = *(const half8*)(wgp);
      half8 nb1 = *(const half8*)(wgp + 1024);
      half8 nb2 = *(const half8*)(wgp + 2048);
      half8 nb3 = *(const half8*)(wgp + 3072);
      f32x4 cv[2][2];
      const int cg = w << 1;               // this wave's two cx granule positions

#pragma unroll
      for (int s = 0; s < 16; ++s) {
        half8 b0 = nb0, b1 = nb1, b2 = nb2, b3 = nb3;
        if (s < 15) {
          const char* p = wgp + ((s + 1) << 12);
          nb0 = *(const half8*)(p);
          nb1 = *(const half8*)(p + 1024);
          nb2 = *(const half8*)(p + 2048);
          nb3 = *(const half8*)(p + 3072);
        }
        if (s == 10) {                     // issue cx loads; ~5 steps of MFMA left >> HBM latency
#pragma unroll
          for (int gi = 0; gi < 2; ++gi) {
            int g2 = cg + gi, m = g2 >> 3, ss = g2 & 7;
            const float* p = cx + (size_t)(rbase + (m << 4) + l15) * 256 + (ss << 5) + kq8;
            cv[gi][0] = *(const f32x4*)p;
            cv[gi][1] = *(const f32x4*)(p + 4);
          }
        }
        const int so = ((s >> 3) << 15) + ((s & 7) << 10);
#pragma unroll
        for (int m = 0; m < 4; ++m) {
          half8 a = *(const half8*)(a0 + so + (m << 13));
          acc[0][m] = __builtin_amdgcn_mfma_f32_16x16x32_f16(a, b0, acc[0][m], 0, 0, 0);
          acc[1][m] = __builtin_amdgcn_mfma_f32_16x16x32_f16(a, b1, acc[1][m], 0, 0, 0);
          acc[2][m] = __builtin_amdgcn_mfma_f32_16x16x32_f16(a, b2, acc[2][m], 0, 0, 0);
          acc[3][m] = __builtin_amdgcn_mfma_f32_16x16x32_f16(a, b3, acc[3][m], 0, 0, 0);
        }
      }

      // flush cx hi/lo granules FIRST (cv dies before the gate-finish crunch)
#pragma unroll
      for (int gi = 0; gi < 2; ++gi) {
        half8 hv, lv;
#pragma unroll
        for (int e = 0; e < 4; ++e) {
          hv[e]     = (_Float16)cv[gi][0][e]; lv[e]     = (_Float16)(cv[gi][0][e] - (float)hv[e]);
          hv[e + 4] = (_Float16)cv[gi][1][e]; lv[e + 4] = (_Float16)(cv[gi][1][e] - (float)hv[e + 4]);
        }
        *(half8*)(smem + 65536 + ((cg + gi) << 10) + laneB) = hv;
        *(half8*)(smem + 98304 + ((cg + gi) << 10) + laneB) = lv;
      }

      // per-m interleaved gate finish: acc[*][m] dies as packed f16 results are built
#pragma unroll
      for (int m = 0; m < 4; ++m)
#pragma unroll
        for (int e = 0; e < 4; ++e) {
          const int ve = ((m & 1) << 2) + e;
          pk_i[m >> 1][ve] = (_Float16)(sigf(acc[0][m][e] + bi) * tanhf_(acc[2][m][e] + bg));
          pk_f[m >> 1][ve] = (_Float16)(sigf(acc[1][m][e] + bfg));
          pk_o[m >> 1][ve] = (_Float16)(sigf(acc[3][m][e] + bo));
        }
    }
    __syncthreads();

    // ================= PHASE B: decomp MFMA + staggered next-stage + epilogue =================
    f32x4 accd[4];
#pragma unroll
    for (int m = 0; m < 4; ++m) accd[m] = fz;

    {
      half8 nbd = *(const half8*)(wdp);
      f32x4 sva[2][2], svb[2][2];
      const int nrbase = rbase + 64;

      auto issue2 = [&](int base, f32x4 (&sv)[2][2]) {
#pragma unroll
        for (int gi = 0; gi < 2; ++gi) {
          int gid = (w << 2) + base + gi;
          int sec = gid >> 5, m = (gid >> 3) & 3, ss = gid & 7;
          const float* p = (sec ? hx : inp) + (size_t)(nrbase + (m << 4) + l15) * 256 + (ss << 5) + kq8;
          sv[gi][0] = *(const f32x4*)p;
          sv[gi][1] = *(const f32x4*)(p + 4);
        }
      };
      auto write2 = [&](int base, const f32x4 (&sv)[2][2]) {
#pragma unroll
        for (int gi = 0; gi < 2; ++gi) {
          half8 hv;
#pragma unroll
          for (int e = 0; e < 4; ++e) { hv[e] = (_Float16)sv[gi][0][e]; hv[e + 4] = (_Float16)sv[gi][1][e]; }
          *(half8*)(smem + (((w << 2) + base + gi) << 10) + laneB) = hv;
        }
      };

#pragma unroll
      for (int s = 0; s < 8; ++s) {
        half8 b = nbd;
        if (s < 7) nbd = *(const half8*)(wdp + ((s + 1) << 10));
        if (s == 1 && more) issue2(0, sva);
        if (s == 4 && more) { write2(0, sva); issue2(2, svb); }
#pragma unroll
        for (int m = 0; m < 4; ++m) {
          half8 ah = *(const half8*)(a1 + (m << 13) + (s << 10));
          half8 al = *(const half8*)(a1 + 32768 + (m << 13) + (s << 10));
          accd[m] = __builtin_amdgcn_mfma_f32_16x16x32_f16(ah, b, accd[m], 0, 0, 0);
          accd[m] = __builtin_amdgcn_mfma_f32_16x16x32_f16(al, b, accd[m], 0, 0, 0);
        }
      }
      if (more) {
        write2(2, svb);
        if (tid < 64) tsh[(((it + 1) & 1) << 6) + tid] = tt[rbase + 64 + tid];
      }
    }

    // epilogue
    const float* tcur = tsh + ((it & 1) << 6);
#pragma unroll
    for (int m = 0; m < 4; ++m) {
      float* po = out + (size_t)(rbase + (m << 4) + er) * 256 + h;
      const char* chp = smem + 65536 + (m << 13) + (er << 4) + hoff;
#pragma unroll
      for (int e = 0; e < 4; ++e) {
        const int ve = ((m & 1) << 2) + e;
        const float tv = tcur[(m << 4) + er + e];
        const float T  = (tv != 0.0f) ? rcpf(tv) : 0.0f;
        const float cxv = (float)*(const _Float16*)(chp + (e << 4))
                        + (float)*(const _Float16*)(chp + 32768 + (e << 4));
        const float cst = tanhf_(accd[m][e] + bdv);
        const float cxa = cxv - cst + T * cst;
        const float cy  = (float)pk_f[m >> 1][ve] * cxa + (float)pk_i[m >> 1][ve];
        const float hy  = (float)pk_o[m >> 1][ve] * tanhf_(cy);
        po[(size_t)e * 256]               = hy;
        po[16777216ull + (size_t)e * 256] = cy;
      }
    }
    __syncthreads();
  }
}

extern "C" void kernel_launch(void* const* d_in, const int* in_sizes, int n_in,
                              void* d_out, int out_size, void* d_ws, size_t ws_size,
                              hipStream_t stream) {
  const float* inp = (const float*)d_in[0];
  const float* t   = (const float*)d_in[1];
  const float* hx  = (const float*)d_in[2];
  const float* cx  = (const float*)d_in[3];
  const float* wih = (const float*)d_in[4];
  const float* whh = (const float*)d_in[5];
  const float* bih = (const float*)d_in[6];
  const float* bhh = (const float*)d_in[7];
  const float* wd  = (const float*)d_in[8];
  const float* bd  = (const float*)d_in[9];
  float* out = (float*)d_out;
  char* wp = (char*)d_ws;   // 1.125 MiB: 1 MiB gate granules + 128 KiB decomp granules

  prepack_kernel<<<256, 512, 0, stream>>>(wih, whh, wd, wp);

  hipFuncSetAttribute((const void*)talstm_kernel,
                      hipFuncAttributeMaxDynamicSharedMemorySize, LDS_BYTES);
  talstm_kernel<<<256, 1024, LDS_BYTES, stream>>>(inp, t, hx, cx, bih, bhh, bd, wp, out);
}

// Round 8
// 169.902 us; speedup vs baseline: 2.8225x; 2.8225x over previous
//
#include <hip/hip_runtime.h>

typedef _Float16 half8 __attribute__((ext_vector_type(8)));
typedef float    f32x4 __attribute__((ext_vector_type(4)));

#define LDS_BYTES (65536 + 128)   // A granules 64K (in|hx|cx_hi|cx_lo) + t[32]

__device__ __forceinline__ float rcpf(float x) { return __builtin_amdgcn_rcpf(x); }
__device__ __forceinline__ float sigf(float x)  { return rcpf(1.0f + __expf(-x)); }
__device__ __forceinline__ float tanhf_(float x){ return 1.0f - 2.0f * rcpf(1.0f + __expf(2.0f * x)); }

// ---------------- prepack: fp32 weights -> f16 MFMA-fragment granules in ws ----------------
// Gate granules (1 MiB @ wp+0): id = ((hb*16 + s)*4 + g), 1 KiB each  [hb-major: one wave's
//   per-hb K-stream = contiguous 64 KiB; 4 gates of a k-slice at imm offsets 0..3072].
//   Lane l byte l*16, elem e = W[g*256 + hb*16 + (l&15)][s*32 + (l>>4)*8 + e]; K=512=[Wih|Whh].
// Decomp granules (128 KiB @ wp+1MiB): id = (hb*8 + s), value = Wd[k][h] (f16 hi; lo
//   correction comes from splitting cx, reusing the SAME B fragment for both passes).
__global__ __launch_bounds__(512) void prepack_kernel(
    const float* __restrict__ wih, const float* __restrict__ whh,
    const float* __restrict__ wd, char* __restrict__ wp)
{
  int idx = blockIdx.x * 512 + threadIdx.x;
  if (idx < 65536) {                       // gates: 8 consecutive k per thread
    int n  = idx >> 6;                     // 0..1023 = g*256 + h
    int k8 = (idx & 63) << 3;              // 0..504
    const float* src = (k8 < 256) ? (wih + n * 256 + k8) : (whh + n * 256 + (k8 - 256));
    f32x4 v0 = *(const f32x4*)src;
    f32x4 v1 = *(const f32x4*)(src + 4);
    half8 hv;
#pragma unroll
    for (int e = 0; e < 4; ++e) { hv[e] = (_Float16)v0[e]; hv[e + 4] = (_Float16)v1[e]; }
    int g = n >> 8, h = n & 255;
    int gran = (((h >> 4) << 4) + (k8 >> 5)) * 4 + g;
    int lane = (h & 15) + (((k8 >> 3) & 3) << 4);
    *(half8*)(wp + (gran << 10) + (lane << 4)) = hv;
  } else {                                 // decomp: scalar (coalesced reads over h)
    int i2 = idx - 65536;
    int h = i2 & 255, k = i2 >> 8;
    float v = wd[k * 256 + h];
    int gran = ((h >> 4) << 3) + (k >> 5);
    int lane = (h & 15) + (((k >> 3) & 3) << 4);
    *(_Float16*)(wp + (1 << 20) + (gran << 10) + (lane << 4) + ((k & 7) << 1)) = (_Float16)v;
  }
}

// ---------------- fused TA-LSTM cell: small-tile, 2 blocks/CU, spill-proof ----------------
// 2048 blocks x 512 thr (8 waves); tile = 32 rows x 256 h. LDS 64K -> 2 blocks/CU;
// __launch_bounds__(512,4) -> 16 waves/CU, 128-reg cap. Phase overlap comes from the CO-RESIDENT
// SECOND BLOCK (one block stages/barriers while the other streams MFMAs) - no intra-block pipe.
// Wave w handles h-blocks hb = 2w, 2w+1 SEQUENTIALLY:
//   gate pass (per hb): acc[4][2]=32 + nb 16 + pk 12 + misc ~25  => peak ~85 << 128 (no spill)
//   decomp pass: accd[2][2]=16 + nbd 16 + pk 24 + misc           => ~90
// LDS A layout (fragment-major 1 KiB granules, all ds ops 64x16B linear, conflict-free):
//   in: gid=m*8+s @0K..16K | hx: @16K..32K | cx_hi: @32K..48K | cx_lo: @48K..64K
__global__ __launch_bounds__(512, 4) void talstm_kernel(
    const float* __restrict__ inp, const float* __restrict__ tt,
    const float* __restrict__ hx,  const float* __restrict__ cx,
    const float* __restrict__ bih, const float* __restrict__ bhh,
    const float* __restrict__ bd,  const char* __restrict__ wp,
    float* __restrict__ out)
{
  extern __shared__ __align__(16) char smem[];
  float* tsh = (float*)(smem + 65536);
  const int tid  = threadIdx.x;
  const int lane = tid & 63;
  const int w    = __builtin_amdgcn_readfirstlane(tid >> 6);   // wave 0..7
  const int l15  = lane & 15;
  const int kq8  = (lane >> 4) << 3;
  const int laneB = lane << 4;
  const int rbase = blockIdx.x << 5;       // 32 rows/block

  if (tid < 32) tsh[tid] = tt[rbase + tid];

  // ---- prologue: stage ALL of A (in | hx | cx hi/lo), fragment-major ----
  {
    const float* base = (w < 4) ? inp : hx;
    char* dst = smem + ((w < 4) ? 0 : 16384);
#pragma unroll
    for (int i = 0; i < 4; ++i) {
      int gid = ((w & 3) << 2) + i;        // 0..15: m = gid>>3, ss = gid&7
      int m = gid >> 3, ss = gid & 7;
      const float* p = base + (size_t)(rbase + (m << 4) + l15) * 256 + (ss << 5) + kq8;
      f32x4 v0 = *(const f32x4*)p, v1 = *(const f32x4*)(p + 4);
      half8 hv;
#pragma unroll
      for (int e = 0; e < 4; ++e) { hv[e] = (_Float16)v0[e]; hv[e + 4] = (_Float16)v1[e]; }
      *(half8*)(dst + (gid << 10) + laneB) = hv;
    }
#pragma unroll
    for (int i = 0; i < 2; ++i) {          // cx: hi + lo split
      int c = (w << 1) + i;                // 0..15
      int m = c >> 3, ss = c & 7;
      const float* p = cx + (size_t)(rbase + (m << 4) + l15) * 256 + (ss << 5) + kq8;
      f32x4 v0 = *(const f32x4*)p, v1 = *(const f32x4*)(p + 4);
      half8 hv, lv;
#pragma unroll
      for (int e = 0; e < 4; ++e) {
        hv[e]     = (_Float16)v0[e]; lv[e]     = (_Float16)(v0[e] - (float)hv[e]);
        hv[e + 4] = (_Float16)v1[e]; lv[e + 4] = (_Float16)(v1[e] - (float)hv[e + 4]);
      }
      *(half8*)(smem + 32768 + (c << 10) + laneB) = hv;
      *(half8*)(smem + 49152 + (c << 10) + laneB) = lv;
    }
  }
  __syncthreads();

  // ---- gate passes: hb = 2w, 2w+1 sequentially (keeps liveness small) ----
  half8 pk_ig[2], pk_f[2], pk_o[2];        // packed f16 gate results, slot m*4+e
#pragma unroll
  for (int hb2 = 0; hb2 < 2; ++hb2) {
    const int hb = (w << 1) + hb2;
    const int h  = (hb << 4) + l15;
    const float bi  = bih[h]       + bhh[h];
    const float bfg = bih[256 + h] + bhh[256 + h];
    const float bg  = bih[512 + h] + bhh[512 + h];
    const float bo  = bih[768 + h] + bhh[768 + h];

    f32x4 acc[4][2];                       // [gate][m]
    const f32x4 fz = {0.f, 0.f, 0.f, 0.f};
#pragma unroll
    for (int g = 0; g < 4; ++g) { acc[g][0] = fz; acc[g][1] = fz; }

    const char* wgp = wp + (hb << 16) + laneB;   // s at +s*4096, g at +g*1024
    half8 nb0 = *(const half8*)(wgp);
    half8 nb1 = *(const half8*)(wgp + 1024);
    half8 nb2 = *(const half8*)(wgp + 2048);
    half8 nb3 = *(const half8*)(wgp + 3072);

#pragma unroll
    for (int s = 0; s < 16; ++s) {
      half8 b0 = nb0, b1 = nb1, b2 = nb2, b3 = nb3;
      if (s < 15) {
        const char* p = wgp + ((s + 1) << 12);
        nb0 = *(const half8*)(p);
        nb1 = *(const half8*)(p + 1024);
        nb2 = *(const half8*)(p + 2048);
        nb3 = *(const half8*)(p + 3072);
      }
      const int so = ((s >> 3) << 14) + ((s & 7) << 10);   // sec 16K | ss 1K
#pragma unroll
      for (int m = 0; m < 2; ++m) {
        half8 a = *(const half8*)(smem + so + (m << 13) + laneB);
        acc[0][m] = __builtin_amdgcn_mfma_f32_16x16x32_f16(a, b0, acc[0][m], 0, 0, 0);
        acc[1][m] = __builtin_amdgcn_mfma_f32_16x16x32_f16(a, b1, acc[1][m], 0, 0, 0);
        acc[2][m] = __builtin_amdgcn_mfma_f32_16x16x32_f16(a, b2, acc[2][m], 0, 0, 0);
        acc[3][m] = __builtin_amdgcn_mfma_f32_16x16x32_f16(a, b3, acc[3][m], 0, 0, 0);
      }
    }
    // finish gates -> packed f16 (values in (-1,1); 5e-4 rel err << threshold)
#pragma unroll
    for (int m = 0; m < 2; ++m)
#pragma unroll
      for (int e = 0; e < 4; ++e) {
        const int ve = (m << 2) + e;
        pk_ig[hb2][ve] = (_Float16)(sigf(acc[0][m][e] + bi) * tanhf_(acc[2][m][e] + bg));
        pk_f[hb2][ve]  = (_Float16)(sigf(acc[1][m][e] + bfg));
        pk_o[hb2][ve]  = (_Float16)(sigf(acc[3][m][e] + bo));
      }
  }

  // ---- decomp pass: both hb together (B frags independent, A frags shared) ----
  f32x4 accd[2][2];                        // [hb2][m]
  {
    const f32x4 fz = {0.f, 0.f, 0.f, 0.f};
    accd[0][0] = fz; accd[0][1] = fz; accd[1][0] = fz; accd[1][1] = fz;
    const char* wd0 = wp + (1 << 20) + ((w << 1) << 13) + laneB;   // hb=2w
    const char* wd1 = wd0 + 8192;                                  // hb=2w+1
    half8 nd0 = *(const half8*)(wd0);
    half8 nd1 = *(const half8*)(wd1);
#pragma unroll
    for (int s = 0; s < 8; ++s) {
      half8 b0 = nd0, b1 = nd1;
      if (s < 7) {
        nd0 = *(const half8*)(wd0 + ((s + 1) << 10));
        nd1 = *(const half8*)(wd1 + ((s + 1) << 10));
      }
#pragma unroll
      for (int m = 0; m < 2; ++m) {
        half8 ah = *(const half8*)(smem + 32768 + (m << 13) + (s << 10) + laneB);
        half8 al = *(const half8*)(smem + 49152 + (m << 13) + (s << 10) + laneB);
        accd[0][m] = __builtin_amdgcn_mfma_f32_16x16x32_f16(ah, b0, accd[0][m], 0, 0, 0);
        accd[0][m] = __builtin_amdgcn_mfma_f32_16x16x32_f16(al, b0, accd[0][m], 0, 0, 0);
        accd[1][m] = __builtin_amdgcn_mfma_f32_16x16x32_f16(ah, b1, accd[1][m], 0, 0, 0);
        accd[1][m] = __builtin_amdgcn_mfma_f32_16x16x32_f16(al, b1, accd[1][m], 0, 0, 0);
      }
    }
  }

  // ---- epilogue ----
  const int er = (lane >> 4) << 2;         // C/D row within m-strip = er + e
#pragma unroll
  for (int hb2 = 0; hb2 < 2; ++hb2) {
    const int hb = (w << 1) + hb2;
    const int h  = (hb << 4) + l15;
    const float bdv = bd[h];
    // cx LDS coords for column h: granule ss = hb>>1, lane = (row&15) + (((hb&1)*2+(l15>>3))<<4)
    const int hoff = ((hb >> 1) << 10) + ((((hb & 1) << 1) + (l15 >> 3)) << 8) + ((l15 & 7) << 1);
#pragma unroll
    for (int m = 0; m < 2; ++m) {
      float* po = out + (size_t)(rbase + (m << 4) + er) * 256 + h;
      const char* chp = smem + 32768 + (m << 13) + (er << 4) + hoff;
#pragma unroll
      for (int e = 0; e < 4; ++e) {
        const int ve = (m << 2) + e;
        const float tv = tsh[(m << 4) + er + e];
        const float T  = (tv != 0.0f) ? rcpf(tv) : 0.0f;
        const float cxv = (float)*(const _Float16*)(chp + (e << 4))
                        + (float)*(const _Float16*)(chp + 16384 + (e << 4));
        const float cst = tanhf_(accd[hb2][m][e] + bdv);
        const float cxa = cxv - cst + T * cst;
        const float cy  = (float)pk_f[hb2][ve] * cxa + (float)pk_ig[hb2][ve];
        const float hy  = (float)pk_o[hb2][ve] * tanhf_(cy);
        po[(size_t)e * 256]               = hy;
        po[16777216ull + (size_t)e * 256] = cy;
      }
    }
  }
}

extern "C" void kernel_launch(void* const* d_in, const int* in_sizes, int n_in,
                              void* d_out, int out_size, void* d_ws, size_t ws_size,
                              hipStream_t stream) {
  const float* inp = (const float*)d_in[0];
  const float* t   = (const float*)d_in[1];
  const float* hx  = (const float*)d_in[2];
  const float* cx  = (const float*)d_in[3];
  const float* wih = (const float*)d_in[4];
  const float* whh = (const float*)d_in[5];
  const float* bih = (const float*)d_in[6];
  const float* bhh = (const float*)d_in[7];
  const float* wd  = (const float*)d_in[8];
  const float* bd  = (const float*)d_in[9];
  float* out = (float*)d_out;
  char* wp = (char*)d_ws;   // 1.125 MiB: 1 MiB gate granules + 128 KiB decomp granules

  prepack_kernel<<<256, 512, 0, stream>>>(wih, whh, wd, wp);

  hipFuncSetAttribute((const void*)talstm_kernel,
                      hipFuncAttributeMaxDynamicSharedMemorySize, LDS_BYTES);
  talstm_kernel<<<2048, 512, LDS_BYTES, stream>>>(inp, t, hx, cx, bih, bhh, bd, wp, out);
}

// Round 9
// 155.049 us; speedup vs baseline: 3.0929x; 1.0958x over previous
//
#include <hip/hip_runtime.h>

typedef _Float16 half8 __attribute__((ext_vector_type(8)));
typedef float    f32x4 __attribute__((ext_vector_type(4)));

#define LDS_BYTES (65536 + 256)   // A buffer 64K (in|hx, later cx_hi|cx_lo) + t[64]

__device__ __forceinline__ float rcpf(float x) { return __builtin_amdgcn_rcpf(x); }
__device__ __forceinline__ float sigf(float x)  { return rcpf(1.0f + __expf(-x)); }
__device__ __forceinline__ float tanhf_(float x){ return 1.0f - 2.0f * rcpf(1.0f + __expf(2.0f * x)); }

// ---------------- prepack: fp32 weights -> f16 MFMA-fragment granules in ws ----------------
// Gate granules (1 MiB @ wp+0): id = ((hb*16 + s)*4 + g), 1 KiB each  [hb-major: one wave's
//   per-hb K-stream = contiguous 64 KiB; 4 gates of a k-slice at imm offsets 0..3072].
//   Lane l byte l*16, elem e = W[g*256 + hb*16 + (l&15)][s*32 + (l>>4)*8 + e]; K=512=[Wih|Whh].
// Decomp granules (128 KiB @ wp+1MiB): id = (hb*8 + s), value = Wd[k][h] (f16 hi; lo
//   correction comes from splitting cx, reusing the SAME B fragment for both passes).
__global__ __launch_bounds__(512) void prepack_kernel(
    const float* __restrict__ wih, const float* __restrict__ whh,
    const float* __restrict__ wd, char* __restrict__ wp)
{
  int idx = blockIdx.x * 512 + threadIdx.x;
  if (idx < 65536) {                       // gates: 8 consecutive k per thread
    int n  = idx >> 6;                     // 0..1023 = g*256 + h
    int k8 = (idx & 63) << 3;              // 0..504
    const float* src = (k8 < 256) ? (wih + n * 256 + k8) : (whh + n * 256 + (k8 - 256));
    f32x4 v0 = *(const f32x4*)src;
    f32x4 v1 = *(const f32x4*)(src + 4);
    half8 hv;
#pragma unroll
    for (int e = 0; e < 4; ++e) { hv[e] = (_Float16)v0[e]; hv[e + 4] = (_Float16)v1[e]; }
    int g = n >> 8, h = n & 255;
    int gran = (((h >> 4) << 4) + (k8 >> 5)) * 4 + g;
    int lane = (h & 15) + (((k8 >> 3) & 3) << 4);
    *(half8*)(wp + (gran << 10) + (lane << 4)) = hv;
  } else {                                 // decomp: scalar (coalesced reads over h)
    int i2 = idx - 65536;
    int h = i2 & 255, k = i2 >> 8;
    float v = wd[k * 256 + h];
    int gran = ((h >> 4) << 3) + (k >> 5);
    int lane = (h & 15) + (((k >> 3) & 3) << 4);
    *(_Float16*)(wp + (1 << 20) + (gran << 10) + (lane << 4) + ((k & 7) << 1)) = (_Float16)v;
  }
}

// ---------------- fused TA-LSTM cell: 64-row x 128-h blocks, LDS-reuse, 2 blocks/CU ----------------
// Grid 2048 = 1024 row-tiles x 2 h-halves; block 512 thr (8 waves); wave = 64 rows x 16 h.
// Gate k-slice: 4 b-loads : 16 MFMA (4:1 compute:load, the R4 ratio) with acc[4][4]=64.
// LDS 64 KiB REUSED: phase 1 = in|hx fragment-major granules; phase 2 = cx_hi|cx_lo.
// Liveness plan (128-cap @ 16 waves/CU): gate loop ~100; cv phase pk24+cv32+misc ~75;
// decomp accd16+pk24+misc ~55. 3 barriers, overlapped by co-resident sibling block.
__global__ __launch_bounds__(512, 4) void talstm_kernel(
    const float* __restrict__ inp, const float* __restrict__ tt,
    const float* __restrict__ hx,  const float* __restrict__ cx,
    const float* __restrict__ bih, const float* __restrict__ bhh,
    const float* __restrict__ bd,  const char* __restrict__ wp,
    float* __restrict__ out)
{
  extern __shared__ __align__(16) char smem[];
  float* tsh = (float*)(smem + 65536);
  const int tid  = threadIdx.x;
  const int lane = tid & 63;
  const int w    = __builtin_amdgcn_readfirstlane(tid >> 6);   // wave 0..7
  const int l15  = lane & 15;
  const int kq8  = (lane >> 4) << 3;
  const int laneB = lane << 4;
  const int rbase = (blockIdx.x >> 1) << 6;    // 64 rows
  const int hb    = ((blockIdx.x & 1) << 3) + w;  // h-block 0..15
  const int h     = (hb << 4) + l15;

  // ---- phase 0: stage in+hx (fragment-major granules) + t ----
  {
    const float* base = (w < 4) ? inp : hx;
    char* dst = smem + ((w < 4) ? 0 : 32768);
#pragma unroll
    for (int i = 0; i < 8; ++i) {
      int gid = ((w & 3) << 3) + i;        // 0..31: m = gid>>3, ss = gid&7
      int m = gid >> 3, ss = gid & 7;
      const float* p = base + (size_t)(rbase + (m << 4) + l15) * 256 + (ss << 5) + kq8;
      f32x4 v0 = *(const f32x4*)p, v1 = *(const f32x4*)(p + 4);
      half8 hv;
#pragma unroll
      for (int e = 0; e < 4; ++e) { hv[e] = (_Float16)v0[e]; hv[e + 4] = (_Float16)v1[e]; }
      *(half8*)(dst + (gid << 10) + laneB) = hv;
    }
    if (tid < 64) tsh[tid] = tt[rbase + tid];
  }
  __syncthreads();

  // ---- gate pass: 16 k-slices, 4 b-loads : 16 MFMA ----
  f32x4 acc[4][4];                         // [gate][m]
  {
    const f32x4 fz = {0.f, 0.f, 0.f, 0.f};
#pragma unroll
    for (int g = 0; g < 4; ++g)
#pragma unroll
      for (int m = 0; m < 4; ++m) acc[g][m] = fz;

    const char* wgp = wp + (hb << 16) + laneB;   // s at +s*4096, g at +g*1024
    half8 nb0 = *(const half8*)(wgp);
    half8 nb1 = *(const half8*)(wgp + 1024);
    half8 nb2 = *(const half8*)(wgp + 2048);
    half8 nb3 = *(const half8*)(wgp + 3072);

#pragma unroll
    for (int s = 0; s < 16; ++s) {
      half8 b0 = nb0, b1 = nb1, b2 = nb2, b3 = nb3;
      if (s < 15) {
        const char* p = wgp + ((s + 1) << 12);
        nb0 = *(const half8*)(p);
        nb1 = *(const half8*)(p + 1024);
        nb2 = *(const half8*)(p + 2048);
        nb3 = *(const half8*)(p + 3072);
      }
      const int so = ((s >> 3) << 15) + ((s & 7) << 10);   // sec 32K | ss 1K
#pragma unroll
      for (int m = 0; m < 4; ++m) {
        half8 a = *(const half8*)(smem + so + (m << 13) + laneB);
        acc[0][m] = __builtin_amdgcn_mfma_f32_16x16x32_f16(a, b0, acc[0][m], 0, 0, 0);
        acc[1][m] = __builtin_amdgcn_mfma_f32_16x16x32_f16(a, b1, acc[1][m], 0, 0, 0);
        acc[2][m] = __builtin_amdgcn_mfma_f32_16x16x32_f16(a, b2, acc[2][m], 0, 0, 0);
        acc[3][m] = __builtin_amdgcn_mfma_f32_16x16x32_f16(a, b3, acc[3][m], 0, 0, 0);
      }
    }
  }

  // ---- issue cx stage loads (latency hides under gate finish + barrier wait) ----
  f32x4 cv[4][2];
#pragma unroll
  for (int i = 0; i < 4; ++i) {
    int sg = (w << 2) + i;                 // 0..31 source granules
    int m = sg >> 3, ss = sg & 7;
    const float* p = cx + (size_t)(rbase + (m << 4) + l15) * 256 + (ss << 5) + kq8;
    cv[i][0] = *(const f32x4*)p;
    cv[i][1] = *(const f32x4*)(p + 4);
  }

  // ---- gate finish: acc -> packed f16 (i*g, f, o in (-1,1); 5e-4 rel err << thr) ----
  half8 pk_ig[2], pk_f[2], pk_o[2];        // slot m*4+e -> vec m>>1, elem (m&1)*4+e
  {
    const float bi  = bih[h]       + bhh[h];
    const float bfg = bih[256 + h] + bhh[256 + h];
    const float bg  = bih[512 + h] + bhh[512 + h];
    const float bo  = bih[768 + h] + bhh[768 + h];
#pragma unroll
    for (int m = 0; m < 4; ++m)
#pragma unroll
      for (int e = 0; e < 4; ++e) {
        const int ve = ((m & 1) << 2) + e;
        pk_ig[m >> 1][ve] = (_Float16)(sigf(acc[0][m][e] + bi) * tanhf_(acc[2][m][e] + bg));
        pk_f[m >> 1][ve]  = (_Float16)(sigf(acc[1][m][e] + bfg));
        pk_o[m >> 1][ve]  = (_Float16)(sigf(acc[3][m][e] + bo));
      }
  }
  __syncthreads();                         // all waves done reading in/hx

  // ---- write cx hi/lo granules (overwrites in|hx) ----
#pragma unroll
  for (int i = 0; i < 4; ++i) {
    int sg = (w << 2) + i;
    half8 hv, lv;
#pragma unroll
    for (int e = 0; e < 4; ++e) {
      hv[e]     = (_Float16)cv[i][0][e]; lv[e]     = (_Float16)(cv[i][0][e] - (float)hv[e]);
      hv[e + 4] = (_Float16)cv[i][1][e]; lv[e + 4] = (_Float16)(cv[i][1][e] - (float)hv[e + 4]);
    }
    *(half8*)(smem + (sg << 10) + laneB)         = hv;   // cx_hi @ 0..32K
    *(half8*)(smem + 32768 + (sg << 10) + laneB) = lv;   // cx_lo @ 32..64K
  }
  __syncthreads();                         // cx visible

  // ---- decomp pass: 8 k-slices, 1 b-load : 8 MFMA (hi+lo share b) ----
  f32x4 accd[4];
  {
    const f32x4 fz = {0.f, 0.f, 0.f, 0.f};
#pragma unroll
    for (int m = 0; m < 4; ++m) accd[m] = fz;
    const char* wdp = wp + (1 << 20) + (hb << 13) + laneB;
    half8 nd = *(const half8*)(wdp);
#pragma unroll
    for (int s = 0; s < 8; ++s) {
      half8 b = nd;
      if (s < 7) nd = *(const half8*)(wdp + ((s + 1) << 10));
#pragma unroll
      for (int m = 0; m < 4; ++m) {
        half8 ah = *(const half8*)(smem + (m << 13) + (s << 10) + laneB);
        half8 al = *(const half8*)(smem + 32768 + (m << 13) + (s << 10) + laneB);
        accd[m] = __builtin_amdgcn_mfma_f32_16x16x32_f16(ah, b, accd[m], 0, 0, 0);
        accd[m] = __builtin_amdgcn_mfma_f32_16x16x32_f16(al, b, accd[m], 0, 0, 0);
      }
    }
  }

  // ---- epilogue ----
  const int er = (lane >> 4) << 2;         // C/D row within m-strip = er + e
  const float bdv = bd[h];
  // cx[r][h] readback: granule (m = r>>4, ss = h>>5), lane = (r&15) + ((h>>3)&3)*16, byte (h&7)*2
  const int hoffb = ((h >> 5) << 10) + (((h >> 3) & 3) << 8) + ((h & 7) << 1);
#pragma unroll
  for (int m = 0; m < 4; ++m) {
    float* po = out + (size_t)(rbase + (m << 4) + er) * 256 + h;
    const char* chp = smem + (m << 13) + hoffb + (er << 4);
#pragma unroll
    for (int e = 0; e < 4; ++e) {
      const int ve = ((m & 1) << 2) + e;
      const float tv = tsh[(m << 4) + er + e];
      const float T  = (tv != 0.0f) ? rcpf(tv) : 0.0f;
      const float cxv = (float)*(const _Float16*)(chp + (e << 4))
                      + (float)*(const _Float16*)(chp + 32768 + (e << 4));
      const float cst = tanhf_(accd[m][e] + bdv);
      const float cxa = cxv - cst + T * cst;
      const float cy  = (float)pk_f[m >> 1][ve] * cxa + (float)pk_ig[m >> 1][ve];
      const float hy  = (float)pk_o[m >> 1][ve] * tanhf_(cy);
      po[(size_t)e * 256]               = hy;
      po[16777216ull + (size_t)e * 256] = cy;
    }
  }
}

extern "C" void kernel_launch(void* const* d_in, const int* in_sizes, int n_in,
                              void* d_out, int out_size, void* d_ws, size_t ws_size,
                              hipStream_t stream) {
  const float* inp = (const float*)d_in[0];
  const float* t   = (const float*)d_in[1];
  const float* hx  = (const float*)d_in[2];
  const float* cx  = (const float*)d_in[3];
  const float* wih = (const float*)d_in[4];
  const float* whh = (const float*)d_in[5];
  const float* bih = (const float*)d_in[6];
  const float* bhh = (const float*)d_in[7];
  const float* wd  = (const float*)d_in[8];
  const float* bd  = (const float*)d_in[9];
  float* out = (float*)d_out;
  char* wp = (char*)d_ws;   // 1.125 MiB: 1 MiB gate granules + 128 KiB decomp granules

  prepack_kernel<<<256, 512, 0, stream>>>(wih, whh, wd, wp);

  hipFuncSetAttribute((const void*)talstm_kernel,
                      hipFuncAttributeMaxDynamicSharedMemorySize, LDS_BYTES);
  talstm_kernel<<<2048, 512, LDS_BYTES, stream>>>(inp, t, hx, cx, bih, bhh, bd, wp, out);
}

// Round 11
// 151.311 us; speedup vs baseline: 3.1693x; 1.0247x over previous
//
#include <hip/hip_runtime.h>

typedef _Float16 half8  __attribute__((ext_vector_type(8)));
typedef __fp16   fp16x2 __attribute__((ext_vector_type(2)));   // cvt_pkrtz result type
typedef float    f32x4  __attribute__((ext_vector_type(4)));

#define LDS_BYTES (65536 + 256)   // A buffer 64K (in|hx, later cx_hi|cx_lo) + t[64]

__device__ __forceinline__ float rcpf(float x) { return __builtin_amdgcn_rcpf(x); }
__device__ __forceinline__ float sigf(float x)  { return rcpf(1.0f + __expf(-x)); }
__device__ __forceinline__ float tanhf_(float x){ return 1.0f - 2.0f * rcpf(1.0f + __expf(2.0f * x)); }

// pack 8 f32 -> half8 fragment via v_cvt_pkrtz_f16_f32 (4 insts instead of 8 cvt)
__device__ __forceinline__ half8 pk8(f32x4 lo, f32x4 hi) {
  union { half8 h; fp16x2 p[4]; } u;
  u.p[0] = __builtin_amdgcn_cvt_pkrtz(lo[0], lo[1]);
  u.p[1] = __builtin_amdgcn_cvt_pkrtz(lo[2], lo[3]);
  u.p[2] = __builtin_amdgcn_cvt_pkrtz(hi[0], hi[1]);
  u.p[3] = __builtin_amdgcn_cvt_pkrtz(hi[2], hi[3]);
  return u.h;
}

// ---------------- prepack: fp32 weights -> f16 MFMA-fragment granules in ws ----------------
// Gate granules (1 MiB @ wp+0): id = ((hb*16 + s)*4 + g), 1 KiB each  [hb-major: one wave's
//   per-hb K-stream = contiguous 64 KiB; 4 gates of a k-slice at imm offsets 0..3072].
//   Lane l byte l*16, elem e = W[g*256 + hb*16 + (l&15)][s*32 + (l>>4)*8 + e]; K=512=[Wih|Whh].
// Decomp granules (128 KiB @ wp+1MiB): id = (hb*8 + s), value = Wd[k][h] (f16 hi; lo
//   correction comes from splitting cx, reusing the SAME B fragment for both passes).
__global__ __launch_bounds__(512) void prepack_kernel(
    const float* __restrict__ wih, const float* __restrict__ whh,
    const float* __restrict__ wd, char* __restrict__ wp)
{
  int idx = blockIdx.x * 512 + threadIdx.x;
  if (idx < 65536) {                       // gates: 8 consecutive k per thread
    int n  = idx >> 6;                     // 0..1023 = g*256 + h
    int k8 = (idx & 63) << 3;              // 0..504
    const float* src = (k8 < 256) ? (wih + n * 256 + k8) : (whh + n * 256 + (k8 - 256));
    f32x4 v0 = *(const f32x4*)src;
    f32x4 v1 = *(const f32x4*)(src + 4);
    half8 hv;
#pragma unroll
    for (int e = 0; e < 4; ++e) { hv[e] = (_Float16)v0[e]; hv[e + 4] = (_Float16)v1[e]; }
    int g = n >> 8, h = n & 255;
    int gran = (((h >> 4) << 4) + (k8 >> 5)) * 4 + g;
    int lane = (h & 15) + (((k8 >> 3) & 3) << 4);
    *(half8*)(wp + (gran << 10) + (lane << 4)) = hv;
  } else {                                 // decomp: scalar (coalesced reads over h)
    int i2 = idx - 65536;
    int h = i2 & 255, k = i2 >> 8;
    float v = wd[k * 256 + h];
    int gran = ((h >> 4) << 3) + (k >> 5);
    int lane = (h & 15) + (((k >> 3) & 3) << 4);
    *(_Float16*)(wp + (1 << 20) + (gran << 10) + (lane << 4) + ((k & 7) << 1)) = (_Float16)v;
  }
}

// ---------------- fused TA-LSTM cell: 64r x 128h blocks, depth-2 W prefetch ----------------
// Grid 2048 = 1024 row-tiles x 2 h-halves; block 512 thr (8 waves); wave = 64 rows x 16 h.
// LDS 64 KiB reused (in|hx -> cx_hi|cx_lo); 2 blocks/CU, 16 waves/CU, 128-reg cap.
// Depth-2 W prefetch (ping-pong bX/bY, issue-to-use ~2 iters ~600cyc) tolerates the bursty
// L2 latency from lockstep waves.  Biases + decomp b-frags preloaded so no phase starts cold.
__global__ __launch_bounds__(512, 4) void talstm_kernel(
    const float* __restrict__ inp, const float* __restrict__ tt,
    const float* __restrict__ hx,  const float* __restrict__ cx,
    const float* __restrict__ bih, const float* __restrict__ bhh,
    const float* __restrict__ bd,  const char* __restrict__ wp,
    float* __restrict__ out)
{
  extern __shared__ __align__(16) char smem[];
  float* tsh = (float*)(smem + 65536);
  const int tid  = threadIdx.x;
  const int lane = tid & 63;
  const int w    = __builtin_amdgcn_readfirstlane(tid >> 6);   // wave 0..7
  const int l15  = lane & 15;
  const int kq8  = (lane >> 4) << 3;
  const int laneB = lane << 4;
  const int rbase = (blockIdx.x >> 1) << 6;       // 64 rows
  const int hb    = ((blockIdx.x & 1) << 3) + w;  // h-block 0..15
  const int h     = (hb << 4) + l15;

  // bias preload (overlaps the stage-load latency; 5 regs live throughout)
  const float bi  = bih[h]       + bhh[h];
  const float bfg = bih[256 + h] + bhh[256 + h];
  const float bg  = bih[512 + h] + bhh[512 + h];
  const float bo  = bih[768 + h] + bhh[768 + h];
  const float bdv = bd[h];

  // ---- phase 0: stage in+hx (fragment-major granules) + t ----
  {
    const float* base = (w < 4) ? inp : hx;
    char* dst = smem + ((w < 4) ? 0 : 32768);
#pragma unroll
    for (int i = 0; i < 8; ++i) {
      int gid = ((w & 3) << 3) + i;        // 0..31: m = gid>>3, ss = gid&7
      int m = gid >> 3, ss = gid & 7;
      const float* p = base + (size_t)(rbase + (m << 4) + l15) * 256 + (ss << 5) + kq8;
      f32x4 v0 = *(const f32x4*)p, v1 = *(const f32x4*)(p + 4);
      *(half8*)(dst + (gid << 10) + laneB) = pk8(v0, v1);
    }
    if (tid < 64) tsh[tid] = tt[rbase + tid];
  }

  // preload gate b-frags for s=0 (X) and s=1 (Y) BEFORE the barrier (no LDS dependency)
  const char* wgp = wp + (hb << 16) + laneB;   // s at +s*4096, g at +g*1024
  half8 bX0 = *(const half8*)(wgp);
  half8 bX1 = *(const half8*)(wgp + 1024);
  half8 bX2 = *(const half8*)(wgp + 2048);
  half8 bX3 = *(const half8*)(wgp + 3072);
  half8 bY0 = *(const half8*)(wgp + 4096);
  half8 bY1 = *(const half8*)(wgp + 5120);
  half8 bY2 = *(const half8*)(wgp + 6144);
  half8 bY3 = *(const half8*)(wgp + 7168);

  __syncthreads();

  // ---- gate pass: 16 k-slices, unroll-2 ping-pong, depth-2 W prefetch ----
  f32x4 acc[4][4];                         // [gate][m]
  {
    const f32x4 fz = {0.f, 0.f, 0.f, 0.f};
#pragma unroll
    for (int g = 0; g < 4; ++g)
#pragma unroll
      for (int m = 0; m < 4; ++m) acc[g][m] = fz;

#pragma unroll
    for (int sp = 0; sp < 8; ++sp) {
      const int s0 = sp << 1, s1 = s0 + 1;
      {
        const int so = ((s0 >> 3) << 15) + ((s0 & 7) << 10);
#pragma unroll
        for (int m = 0; m < 4; ++m) {
          half8 a = *(const half8*)(smem + so + (m << 13) + laneB);
          acc[0][m] = __builtin_amdgcn_mfma_f32_16x16x32_f16(a, bX0, acc[0][m], 0, 0, 0);
          acc[1][m] = __builtin_amdgcn_mfma_f32_16x16x32_f16(a, bX1, acc[1][m], 0, 0, 0);
          acc[2][m] = __builtin_amdgcn_mfma_f32_16x16x32_f16(a, bX2, acc[2][m], 0, 0, 0);
          acc[3][m] = __builtin_amdgcn_mfma_f32_16x16x32_f16(a, bX3, acc[3][m], 0, 0, 0);
        }
        if (s0 < 14) {                     // refill X for s0+2 (used ~2 iters later)
          const char* p = wgp + ((s0 + 2) << 12);
          bX0 = *(const half8*)(p);
          bX1 = *(const half8*)(p + 1024);
          bX2 = *(const half8*)(p + 2048);
          bX3 = *(const half8*)(p + 3072);
        }
      }
      {
        const int so = ((s1 >> 3) << 15) + ((s1 & 7) << 10);
#pragma unroll
        for (int m = 0; m < 4; ++m) {
          half8 a = *(const half8*)(smem + so + (m << 13) + laneB);
          acc[0][m] = __builtin_amdgcn_mfma_f32_16x16x32_f16(a, bY0, acc[0][m], 0, 0, 0);
          acc[1][m] = __builtin_amdgcn_mfma_f32_16x16x32_f16(a, bY1, acc[1][m], 0, 0, 0);
          acc[2][m] = __builtin_amdgcn_mfma_f32_16x16x32_f16(a, bY2, acc[2][m], 0, 0, 0);
          acc[3][m] = __builtin_amdgcn_mfma_f32_16x16x32_f16(a, bY3, acc[3][m], 0, 0, 0);
        }
        if (s1 < 15) {                     // refill Y for s1+2
          const char* p = wgp + ((s1 + 2) << 12);
          bY0 = *(const half8*)(p);
          bY1 = *(const half8*)(p + 1024);
          bY2 = *(const half8*)(p + 2048);
          bY3 = *(const half8*)(p + 3072);
        }
      }
    }
  }

  // ---- issue cx stage loads (latency hides under gate finish + barrier wait) ----
  f32x4 cv[4][2];
#pragma unroll
  for (int i = 0; i < 4; ++i) {
    int sg = (w << 2) + i;                 // 0..31 source granules
    int m = sg >> 3, ss = sg & 7;
    const float* p = cx + (size_t)(rbase + (m << 4) + l15) * 256 + (ss << 5) + kq8;
    cv[i][0] = *(const f32x4*)p;
    cv[i][1] = *(const f32x4*)(p + 4);
  }

  // ---- gate finish: acc -> packed f16 (i*g, f, o in (-1,1); rel err << thr) ----
  fp16x2 pk_ig[8], pk_f[8], pk_o[8];       // [m*2 + (e>>1)][e&1], 24 VGPRs
#pragma unroll
  for (int m = 0; m < 4; ++m) {
    f32x4 vig, vf, vo;
#pragma unroll
    for (int e = 0; e < 4; ++e) {
      vig[e] = sigf(acc[0][m][e] + bi) * tanhf_(acc[2][m][e] + bg);
      vf[e]  = sigf(acc[1][m][e] + bfg);
      vo[e]  = sigf(acc[3][m][e] + bo);
    }
    pk_ig[(m << 1)]     = __builtin_amdgcn_cvt_pkrtz(vig[0], vig[1]);
    pk_ig[(m << 1) + 1] = __builtin_amdgcn_cvt_pkrtz(vig[2], vig[3]);
    pk_f[(m << 1)]      = __builtin_amdgcn_cvt_pkrtz(vf[0], vf[1]);
    pk_f[(m << 1) + 1]  = __builtin_amdgcn_cvt_pkrtz(vf[2], vf[3]);
    pk_o[(m << 1)]      = __builtin_amdgcn_cvt_pkrtz(vo[0], vo[1]);
    pk_o[(m << 1) + 1]  = __builtin_amdgcn_cvt_pkrtz(vo[2], vo[3]);
  }

  // preload decomp b-frags (independent of LDS; covers the barrier + cx-write window)
  const char* wdp = wp + (1 << 20) + (hb << 13) + laneB;
  half8 nd0 = *(const half8*)(wdp);
  half8 nd1 = *(const half8*)(wdp + 1024);

  __syncthreads();                         // all waves done reading in/hx

  // ---- write cx hi/lo granules (overwrites in|hx) ----
#pragma unroll
  for (int i = 0; i < 4; ++i) {
    int sg = (w << 2) + i;
    half8 hv = pk8(cv[i][0], cv[i][1]);
    f32x4 l0, l1;
#pragma unroll
    for (int e = 0; e < 4; ++e) {
      l0[e] = cv[i][0][e] - (float)hv[e];
      l1[e] = cv[i][1][e] - (float)hv[e + 4];
    }
    *(half8*)(smem + (sg << 10) + laneB)         = hv;          // cx_hi @ 0..32K
    *(half8*)(smem + 32768 + (sg << 10) + laneB) = pk8(l0, l1); // cx_lo @ 32..64K
  }
  __syncthreads();                         // cx visible

  // ---- decomp pass: 8 k-slices, unroll-2 ping-pong (hi+lo share b) ----
  f32x4 accd[4];
  {
    const f32x4 fz = {0.f, 0.f, 0.f, 0.f};
#pragma unroll
    for (int m = 0; m < 4; ++m) accd[m] = fz;
#pragma unroll
    for (int sp = 0; sp < 4; ++sp) {
      const int s0 = sp << 1, s1 = s0 + 1;
#pragma unroll
      for (int m = 0; m < 4; ++m) {
        half8 ah = *(const half8*)(smem + (m << 13) + (s0 << 10) + laneB);
        half8 al = *(const half8*)(smem + 32768 + (m << 13) + (s0 << 10) + laneB);
        accd[m] = __builtin_amdgcn_mfma_f32_16x16x32_f16(ah, nd0, accd[m], 0, 0, 0);
        accd[m] = __builtin_amdgcn_mfma_f32_16x16x32_f16(al, nd0, accd[m], 0, 0, 0);
      }
      if (s0 < 6) nd0 = *(const half8*)(wdp + ((s0 + 2) << 10));
#pragma unroll
      for (int m = 0; m < 4; ++m) {
        half8 ah = *(const half8*)(smem + (m << 13) + (s1 << 10) + laneB);
        half8 al = *(const half8*)(smem + 32768 + (m << 13) + (s1 << 10) + laneB);
        accd[m] = __builtin_amdgcn_mfma_f32_16x16x32_f16(ah, nd1, accd[m], 0, 0, 0);
        accd[m] = __builtin_amdgcn_mfma_f32_16x16x32_f16(al, nd1, accd[m], 0, 0, 0);
      }
      if (s1 < 7) nd1 = *(const half8*)(wdp + ((s1 + 2) << 10));
    }
  }

  // ---- epilogue ----
  const int er = (lane >> 4) << 2;         // C/D row within m-strip = er + e
  // cx[r][h] readback: granule (m = r>>4, ss = h>>5), lane = (r&15) + ((h>>3)&3)*16, byte (h&7)*2
  const int hoffb = ((h >> 5) << 10) + (((h >> 3) & 3) << 8) + ((h & 7) << 1);
#pragma unroll
  for (int m = 0; m < 4; ++m) {
    float* po = out + (size_t)(rbase + (m << 4) + er) * 256 + h;
    const char* chp = smem + (m << 13) + hoffb + (er << 4);
#pragma unroll
    for (int e = 0; e < 4; ++e) {
      const float tv = tsh[(m << 4) + er + e];
      const float T  = (tv != 0.0f) ? rcpf(tv) : 0.0f;
      const float cxv = (float)*(const _Float16*)(chp + (e << 4))
                      + (float)*(const _Float16*)(chp + 32768 + (e << 4));
      const float cst = tanhf_(accd[m][e] + bdv);
      const float cxa = cxv - cst + T * cst;
      const float cy  = (float)pk_f[(m << 1) + (e >> 1)][e & 1] * cxa
                      + (float)pk_ig[(m << 1) + (e >> 1)][e & 1];
      const float hy  = (float)pk_o[(m << 1) + (e >> 1)][e & 1] * tanhf_(cy);
      po[(size_t)e * 256]               = hy;
      po[16777216ull + (size_t)e * 256] = cy;
    }
  }
}

extern "C" void kernel_launch(void* const* d_in, const int* in_sizes, int n_in,
                              void* d_out, int out_size, void* d_ws, size_t ws_size,
                              hipStream_t stream) {
  const float* inp = (const float*)d_in[0];
  const float* t   = (const float*)d_in[1];
  const float* hx  = (const float*)d_in[2];
  const float* cx  = (const float*)d_in[3];
  const float* wih = (const float*)d_in[4];
  const float* whh = (const float*)d_in[5];
  const float* bih = (const float*)d_in[6];
  const float* bhh = (const float*)d_in[7];
  const float* wd  = (const float*)d_in[8];
  const float* bd  = (const float*)d_in[9];
  float* out = (float*)d_out;
  char* wp = (char*)d_ws;   // 1.125 MiB: 1 MiB gate granules + 128 KiB decomp granules

  prepack_kernel<<<256, 512, 0, stream>>>(wih, whh, wd, wp);

  hipFuncSetAttribute((const void*)talstm_kernel,
                      hipFuncAttributeMaxDynamicSharedMemorySize, LDS_BYTES);
  talstm_kernel<<<2048, 512, LDS_BYTES, stream>>>(inp, t, hx, cx, bih, bhh, bd, wp, out);
}